// Round 1
// baseline (548.247 us; speedup 1.0000x reference)
//
#include <hip/hip_runtime.h>
#include <math.h>

typedef __bf16 bf16;
typedef __bf16 bf16x8 __attribute__((ext_vector_type(8)));
typedef __bf16 bf16x4 __attribute__((ext_vector_type(4)));
typedef float f32x4 __attribute__((ext_vector_type(4)));

#define B_DIM 2
#define S_LEN 2048
#define H_DIM 2048
#define NH 16
#define NKV 4
#define HD 128

// ---------------- cast fp32 -> bf16 (vectorized x4) ----------------
__global__ void cast_kernel(const float* __restrict__ src, bf16* __restrict__ dst, int n4) {
    int i = blockIdx.x * 256 + threadIdx.x;
    if (i >= n4) return;
    float4 f = ((const float4*)src)[i];
    bf16x4 o = { (bf16)f.x, (bf16)f.y, (bf16)f.z, (bf16)f.w };
    *(bf16x4*)(dst + (size_t)i * 4) = o;
}

// ---------------- bt-GEMM: C[M][N] = A[M][K] * Bt[N][K]^T, fp32 out ----------------
// 128x128 tile, BK=32, 4 waves each 64x64 (4x4 grid of 16x16x32 mfma)
__global__ __launch_bounds__(256) void gemm_bt(const bf16* __restrict__ A,
                                               const bf16* __restrict__ Bt,
                                               float* __restrict__ C,
                                               int M, int N, int K) {
    __shared__ __align__(16) bf16 As[128][40];  // +8 pad: 2-way bank alias only
    __shared__ __align__(16) bf16 Bs[128][40];
    const int t = threadIdx.x;
    const int lane = t & 63, w = t >> 6;
    const int wm = (w & 1) * 64, wn = (w >> 1) * 64;
    const int lr = lane & 15, quad = lane >> 4;
    const int m0 = blockIdx.x * 128, n0 = blockIdx.y * 128;
    const int srow = t >> 1, shalf = (t & 1) * 16;
    const bf16* ga = A + (size_t)(m0 + srow) * K + shalf;
    const bf16* gb = Bt + (size_t)(n0 + srow) * K + shalf;
    f32x4 acc[4][4];
#pragma unroll
    for (int i = 0; i < 4; i++)
#pragma unroll
        for (int j = 0; j < 4; j++) acc[i][j] = (f32x4){0.f, 0.f, 0.f, 0.f};

    for (int k0 = 0; k0 < K; k0 += 32) {
        __syncthreads();
        bf16x8 a0 = *(const bf16x8*)(ga + k0);
        bf16x8 a1 = *(const bf16x8*)(ga + k0 + 8);
        bf16x8 b0 = *(const bf16x8*)(gb + k0);
        bf16x8 b1 = *(const bf16x8*)(gb + k0 + 8);
        *(bf16x8*)&As[srow][shalf]     = a0;
        *(bf16x8*)&As[srow][shalf + 8] = a1;
        *(bf16x8*)&Bs[srow][shalf]     = b0;
        *(bf16x8*)&Bs[srow][shalf + 8] = b1;
        __syncthreads();
        bf16x8 af[4], bfr[4];
#pragma unroll
        for (int i = 0; i < 4; i++) af[i] = *(const bf16x8*)&As[wm + i * 16 + lr][quad * 8];
#pragma unroll
        for (int j = 0; j < 4; j++) bfr[j] = *(const bf16x8*)&Bs[wn + j * 16 + lr][quad * 8];
#pragma unroll
        for (int i = 0; i < 4; i++)
#pragma unroll
            for (int j = 0; j < 4; j++)
                acc[i][j] = __builtin_amdgcn_mfma_f32_16x16x32_bf16(af[i], bfr[j], acc[i][j], 0, 0, 0);
    }
#pragma unroll
    for (int i = 0; i < 4; i++) {
        int m = m0 + wm + i * 16 + quad * 4;
#pragma unroll
        for (int j = 0; j < 4; j++) {
            int n = n0 + wn + j * 16 + lr;
#pragma unroll
            for (int r = 0; r < 4; r++)
                C[(size_t)(m + r) * N + n] = acc[i][j][r];
        }
    }
}

// ---------------- RoPE + RMSNorm + layout; V written transposed (d-major) ----------------
// one block per token; qkv row = [Q 2048 | K 512 | V 512] fp32
__global__ __launch_bounds__(256) void rope_rms(const float* __restrict__ qkv,
                                                const float* __restrict__ qw,
                                                const float* __restrict__ kw,
                                                bf16* __restrict__ qb,
                                                bf16* __restrict__ kb,
                                                bf16* __restrict__ vt) {
    const int tok = blockIdx.x;
    const int b = tok >> 11, s = tok & (S_LEN - 1);
    const int lane = threadIdx.x & 63, w = threadIdx.x >> 6;
    const float* row = qkv + (size_t)tok * 3072;
    // inv_freq = 10000^(-lane/64)
    const float inv = expf(-(float)lane * (9.210340371976184f / 64.f));
    const float ang = (float)s * inv;
    float s_, c_;
    sincosf(ang, &s_, &c_);
    const float wq1 = qw[lane], wq2 = qw[lane + 64];
    const float wk1 = kw[lane], wk2 = kw[lane + 64];
    for (int u = w; u < 24; u += 4) {
        if (u < 16) {  // Q head
            const float x1 = row[u * 128 + lane], x2 = row[u * 128 + 64 + lane];
            float y1 = x1 * c_ - x2 * s_;
            float y2 = x2 * c_ + x1 * s_;
            float ss = y1 * y1 + y2 * y2;
#pragma unroll
            for (int m = 1; m < 64; m <<= 1) ss += __shfl_xor(ss, m);
            const float r = rsqrtf(ss * (1.f / 128.f) + 1e-6f);
            size_t o = ((size_t)(b * NH + u) * S_LEN + s) * HD;
            qb[o + lane]      = (bf16)(y1 * r * wq1);
            qb[o + 64 + lane] = (bf16)(y2 * r * wq2);
        } else if (u < 20) {  // K head
            const int kh = u - 16;
            const float x1 = row[2048 + kh * 128 + lane], x2 = row[2048 + kh * 128 + 64 + lane];
            float y1 = x1 * c_ - x2 * s_;
            float y2 = x2 * c_ + x1 * s_;
            float ss = y1 * y1 + y2 * y2;
#pragma unroll
            for (int m = 1; m < 64; m <<= 1) ss += __shfl_xor(ss, m);
            const float r = rsqrtf(ss * (1.f / 128.f) + 1e-6f);
            size_t o = ((size_t)(b * NKV + kh) * S_LEN + s) * HD;
            kb[o + lane]      = (bf16)(y1 * r * wk1);
            kb[o + 64 + lane] = (bf16)(y2 * r * wk2);
        } else {  // V head: pure cast, transposed to [d][s]
            const int vh = u - 20;
            const float x1 = row[2560 + vh * 128 + lane], x2 = row[2560 + vh * 128 + 64 + lane];
            size_t o = ((size_t)(b * NKV + vh) * HD + lane) * S_LEN + s;
            vt[o] = (bf16)x1;
            vt[o + (size_t)64 * S_LEN] = (bf16)x2;
        }
    }
}

// ---------------- flash attention (causal, GQA) ----------------
// block = 4 waves; BM=64 q-rows (16/wave); BN=32 keys/tile
__global__ __launch_bounds__(256) void flash(const bf16* __restrict__ qg,
                                             const bf16* __restrict__ kg,
                                             const bf16* __restrict__ vg,
                                             bf16* __restrict__ attn) {
    const int qt = blockIdx.x, h = blockIdx.y, b = blockIdx.z;
    const int kvh = h >> 2;
    const bf16* qptr = qg + (size_t)(b * NH + h) * S_LEN * HD;
    const bf16* kptr = kg + (size_t)(b * NKV + kvh) * S_LEN * HD;
    const bf16* vptr = vg + (size_t)(b * NKV + kvh) * HD * S_LEN;  // [d][s]
    __shared__ __align__(16) bf16 Ks[32][136];   // [key][d] +8 pad
    __shared__ __align__(16) bf16 Vs[128][40];   // [d][key] +8 pad (V^T tile)
    __shared__ __align__(16) bf16 Ps[4][16][40]; // per-wave P round-trip
    const int t = threadIdx.x, lane = t & 63, w = t >> 6, lr = lane & 15, quad = lane >> 4;
    const int qb0 = qt * 64;
    bf16x8 qf[4];
    {
        const bf16* qrow = qptr + (size_t)(qb0 + w * 16 + lr) * HD + quad * 8;
#pragma unroll
        for (int c = 0; c < 4; c++) qf[c] = *(const bf16x8*)(qrow + c * 32);
    }
    f32x4 o[8];
#pragma unroll
    for (int j = 0; j < 8; j++) o[j] = (f32x4){0.f, 0.f, 0.f, 0.f};
    float mi[4] = {-INFINITY, -INFINITY, -INFINITY, -INFINITY};
    float li[4] = {0.f, 0.f, 0.f, 0.f};
    const int rowend = qb0 + w * 16 + 15;
    const int ntile = (qb0 + 63) / 32 + 1;
    const float scale = 0.08838834764831845f;  // 1/sqrt(128)
    const int skk = t >> 3, sdo = (t & 7) * 16;  // K staging: 32 rows x 128
    const int svd = t >> 1, svo = (t & 1) * 16;  // V staging: 128 rows x 32

    for (int kt = 0; kt < ntile; ++kt) {
        const int kbase = kt * 32;
        __syncthreads();
        {
            const bf16* g = kptr + (size_t)(kbase + skk) * HD + sdo;
            bf16x8 v0 = *(const bf16x8*)g, v1 = *(const bf16x8*)(g + 8);
            *(bf16x8*)&Ks[skk][sdo]     = v0;
            *(bf16x8*)&Ks[skk][sdo + 8] = v1;
            const bf16* gv = vptr + (size_t)svd * S_LEN + kbase + svo;
            bf16x8 u0 = *(const bf16x8*)gv, u1 = *(const bf16x8*)(gv + 8);
            *(bf16x8*)&Vs[svd][svo]     = u0;
            *(bf16x8*)&Vs[svd][svo + 8] = u1;
        }
        __syncthreads();
        const bool active = (kbase <= rowend);
        if (active) {
            f32x4 sv[2];
#pragma unroll
            for (int n16 = 0; n16 < 2; n16++) {
                f32x4 sacc = (f32x4){0.f, 0.f, 0.f, 0.f};
#pragma unroll
                for (int c = 0; c < 4; c++) {
                    bf16x8 kf = *(const bf16x8*)&Ks[n16 * 16 + lr][c * 32 + quad * 8];
                    sacc = __builtin_amdgcn_mfma_f32_16x16x32_bf16(qf[c], kf, sacc, 0, 0, 0);
                }
                sv[n16] = sacc;
            }
            const int key0 = kbase + lr;
#pragma unroll
            for (int r = 0; r < 4; r++) {
                const int qrow = qb0 + w * 16 + quad * 4 + r;
                float v0 = (key0 <= qrow)      ? sv[0][r] * scale : -1e30f;
                float v1 = (key0 + 16 <= qrow) ? sv[1][r] * scale : -1e30f;
                float rmax = fmaxf(v0, v1);
#pragma unroll
                for (int m = 1; m < 16; m <<= 1) rmax = fmaxf(rmax, __shfl_xor(rmax, m));
                const float mnew = fmaxf(mi[r], rmax);
                const float alpha = __expf(mi[r] - mnew);
                const float p0 = __expf(v0 - mnew);
                const float p1 = __expf(v1 - mnew);
                float ps = p0 + p1;
#pragma unroll
                for (int m = 1; m < 16; m <<= 1) ps += __shfl_xor(ps, m);
                li[r] = li[r] * alpha + ps;
                mi[r] = mnew;
#pragma unroll
                for (int j = 0; j < 8; j++) o[j][r] *= alpha;
                Ps[w][quad * 4 + r][lr]      = (bf16)p0;
                Ps[w][quad * 4 + r][16 + lr] = (bf16)p1;
            }
        }
        __syncthreads();  // P C-layout -> A-layout round trip
        if (active) {
            bf16x8 pf = *(const bf16x8*)&Ps[w][lr][quad * 8];
#pragma unroll
            for (int j16 = 0; j16 < 8; j16++) {
                bf16x8 vf = *(const bf16x8*)&Vs[j16 * 16 + lr][quad * 8];
                o[j16] = __builtin_amdgcn_mfma_f32_16x16x32_bf16(pf, vf, o[j16], 0, 0, 0);
            }
        }
    }
#pragma unroll
    for (int j = 0; j < 8; j++) {
#pragma unroll
        for (int r = 0; r < 4; r++) {
            const int qrow = qb0 + w * 16 + quad * 4 + r;
            attn[((size_t)(b * S_LEN) + qrow) * (NH * HD) + h * HD + j * 16 + lr] =
                (bf16)(o[j][r] / li[r]);
        }
    }
}

extern "C" void kernel_launch(void* const* d_in, const int* in_sizes, int n_in,
                              void* d_out, int out_size, void* d_ws, size_t ws_size,
                              hipStream_t stream) {
    (void)in_sizes; (void)n_in; (void)out_size; (void)ws_size;
    const float* hs  = (const float*)d_in[0];
    const float* wq  = (const float*)d_in[1];
    const float* wk  = (const float*)d_in[2];
    const float* wv  = (const float*)d_in[3];
    const float* wo  = (const float*)d_in[4];
    const float* qnw = (const float*)d_in[5];
    const float* knw = (const float*)d_in[6];
    float* out = (float*)d_out;

    char* ws = (char*)d_ws;
    size_t off = 0;
    auto alloc = [&](size_t bytes) {
        void* p = ws + off;
        off += (bytes + 255) & ~(size_t)255;
        return p;
    };
    bf16*  hs_bf   = (bf16*)alloc((size_t)4096 * 2048 * 2);
    bf16*  wqkv_bf = (bf16*)alloc((size_t)3072 * 2048 * 2);
    bf16*  wo_bf   = (bf16*)alloc((size_t)2048 * 2048 * 2);
    float* qkv     = (float*)alloc((size_t)4096 * 3072 * 4);
    bf16*  q_bf    = (bf16*)alloc((size_t)B_DIM * NH * S_LEN * HD * 2);
    bf16*  k_bf    = (bf16*)alloc((size_t)B_DIM * NKV * S_LEN * HD * 2);
    bf16*  vt_bf   = (bf16*)alloc((size_t)B_DIM * NKV * HD * S_LEN * 2);
    bf16*  at_bf   = (bf16*)alloc((size_t)4096 * 2048 * 2);

    cast_kernel<<<8192, 256, 0, stream>>>(hs, hs_bf, 2097152);
    cast_kernel<<<4096, 256, 0, stream>>>(wq, wqkv_bf, 1048576);
    cast_kernel<<<1024, 256, 0, stream>>>(wk, wqkv_bf + 4194304, 262144);
    cast_kernel<<<1024, 256, 0, stream>>>(wv, wqkv_bf + 5242880, 262144);
    cast_kernel<<<4096, 256, 0, stream>>>(wo, wo_bf, 1048576);

    gemm_bt<<<dim3(32, 24), 256, 0, stream>>>(hs_bf, wqkv_bf, qkv, 4096, 3072, 2048);
    rope_rms<<<4096, 256, 0, stream>>>(qkv, qnw, knw, q_bf, k_bf, vt_bf);
    flash<<<dim3(32, 16, 2), 256, 0, stream>>>(q_bf, k_bf, vt_bf, at_bf);
    gemm_bt<<<dim3(32, 16), 256, 0, stream>>>(at_bf, wo_bf, out, 4096, 2048, 2048);
}

// Round 2
// 413.054 us; speedup vs baseline: 1.3273x; 1.3273x over previous
//
#include <hip/hip_runtime.h>
#include <math.h>

typedef __bf16 bf16;
typedef __bf16 bf16x8 __attribute__((ext_vector_type(8)));
typedef __bf16 bf16x4 __attribute__((ext_vector_type(4)));
typedef float f32x4 __attribute__((ext_vector_type(4)));

#define B_DIM 2
#define S_LEN 2048
#define H_DIM 2048
#define NH 16
#define NKV 4
#define HD 128

// async global->LDS, 16B per lane; LDS dest = uniform base + lane*16
__device__ __forceinline__ void gl_lds16(const void* g, void* l) {
    __builtin_amdgcn_global_load_lds(
        (const __attribute__((address_space(1))) unsigned int*)g,
        (__attribute__((address_space(3))) unsigned int*)l, 16, 0, 0);
}

// ---------------- cast fp32 -> bf16 (vectorized x4) ----------------
__global__ void cast_kernel(const float* __restrict__ src, bf16* __restrict__ dst, int n4) {
    int i = blockIdx.x * 256 + threadIdx.x;
    if (i >= n4) return;
    float4 f = ((const float4*)src)[i];
    bf16x4 o = { (bf16)f.x, (bf16)f.y, (bf16)f.z, (bf16)f.w };
    *(bf16x4*)(dst + (size_t)i * 4) = o;
}

// ---------------- bt-GEMM: C[M][N] = A[M][K] * Bt[N][K]^T ----------------
// 128x128 tile, BK=32, 4 waves; m97-style global_load_lds staging (unpadded LDS)
template <typename OutT>
__global__ __launch_bounds__(256) void gemm_bt(const bf16* __restrict__ A,
                                               const bf16* __restrict__ Bt,
                                               OutT* __restrict__ C,
                                               int M, int N, int K) {
    __shared__ __align__(16) bf16 As[128 * 32];
    __shared__ __align__(16) bf16 Bs[128 * 32];
    const int t = threadIdx.x;
    const int lane = t & 63, w = t >> 6;
    const int wm = (w & 1) * 64, wn = (w >> 1) * 64;
    const int lr = lane & 15, quad = lane >> 4;
    const int m0 = blockIdx.x * 128, n0 = blockIdx.y * 128;
    const int lrow = lane >> 2, lk = (lane & 3) * 8;
    f32x4 acc[4][4];
#pragma unroll
    for (int i = 0; i < 4; i++)
#pragma unroll
        for (int j = 0; j < 4; j++) acc[i][j] = (f32x4){0.f, 0.f, 0.f, 0.f};

    for (int k0 = 0; k0 < K; k0 += 32) {
        __syncthreads();
#pragma unroll
        for (int i = 0; i < 2; i++) {
            const int r0 = i * 64 + w * 16;
            gl_lds16(A + (size_t)(m0 + r0 + lrow) * K + k0 + lk, &As[r0 * 32]);
            gl_lds16(Bt + (size_t)(n0 + r0 + lrow) * K + k0 + lk, &Bs[r0 * 32]);
        }
        __syncthreads();
        bf16x8 af[4], bfr[4];
#pragma unroll
        for (int i = 0; i < 4; i++) af[i] = *(const bf16x8*)&As[(wm + i * 16 + lr) * 32 + quad * 8];
#pragma unroll
        for (int j = 0; j < 4; j++) bfr[j] = *(const bf16x8*)&Bs[(wn + j * 16 + lr) * 32 + quad * 8];
#pragma unroll
        for (int i = 0; i < 4; i++)
#pragma unroll
            for (int j = 0; j < 4; j++)
                acc[i][j] = __builtin_amdgcn_mfma_f32_16x16x32_bf16(af[i], bfr[j], acc[i][j], 0, 0, 0);
    }
#pragma unroll
    for (int i = 0; i < 4; i++) {
        int m = m0 + wm + i * 16 + quad * 4;
#pragma unroll
        for (int j = 0; j < 4; j++) {
            int n = n0 + wn + j * 16 + lr;
#pragma unroll
            for (int r = 0; r < 4; r++)
                C[(size_t)(m + r) * N + n] = (OutT)acc[i][j][r];
        }
    }
}

// ---------------- RoPE + RMSNorm; K and V written in MFMA-tiled layouts ----------------
// K: [(b,kvh)][dchunk=d>>3 (16)][s (2048)][d&7 (8)]
// V: [(b,kvh)][schunk=s>>3 (256)][d (128)][s&7 (8)]
__global__ __launch_bounds__(256) void rope_rms(const bf16* __restrict__ qkv,
                                                const float* __restrict__ qw,
                                                const float* __restrict__ kw,
                                                bf16* __restrict__ qb,
                                                bf16* __restrict__ kb,
                                                bf16* __restrict__ vt) {
    const int tok = blockIdx.x;
    const int b = tok >> 11, s = tok & (S_LEN - 1);
    const int lane = threadIdx.x & 63, w = threadIdx.x >> 6;
    const bf16* row = qkv + (size_t)tok * 3072;
    const float inv = expf(-(float)lane * (9.210340371976184f / 64.f));
    const float ang = (float)s * inv;
    float s_, c_;
    sincosf(ang, &s_, &c_);
    const float wq1 = qw[lane], wq2 = qw[lane + 64];
    const float wk1 = kw[lane], wk2 = kw[lane + 64];
    for (int u = w; u < 24; u += 4) {
        if (u < 16) {  // Q head: row-major [b,h][s][d]
            const float x1 = (float)row[u * 128 + lane], x2 = (float)row[u * 128 + 64 + lane];
            float y1 = x1 * c_ - x2 * s_;
            float y2 = x2 * c_ + x1 * s_;
            float ss = y1 * y1 + y2 * y2;
#pragma unroll
            for (int m = 1; m < 64; m <<= 1) ss += __shfl_xor(ss, m);
            const float r = rsqrtf(ss * (1.f / 128.f) + 1e-6f);
            size_t o = ((size_t)(b * NH + u) * S_LEN + s) * HD;
            qb[o + lane]      = (bf16)(y1 * r * wq1);
            qb[o + 64 + lane] = (bf16)(y2 * r * wq2);
        } else if (u < 20) {  // K head: tiled
            const int kh = u - 16;
            const float x1 = (float)row[2048 + kh * 128 + lane], x2 = (float)row[2048 + kh * 128 + 64 + lane];
            float y1 = x1 * c_ - x2 * s_;
            float y2 = x2 * c_ + x1 * s_;
            float ss = y1 * y1 + y2 * y2;
#pragma unroll
            for (int m = 1; m < 64; m <<= 1) ss += __shfl_xor(ss, m);
            const float r = rsqrtf(ss * (1.f / 128.f) + 1e-6f);
            size_t base = (size_t)(b * NKV + kh) * 16 * 16384;
            kb[base + (size_t)(lane >> 3) * 16384 + s * 8 + (lane & 7)]       = (bf16)(y1 * r * wk1);
            kb[base + (size_t)(8 + (lane >> 3)) * 16384 + s * 8 + (lane & 7)] = (bf16)(y2 * r * wk2);
        } else {  // V head: tiled cast
            const int vh = u - 20;
            const float x1 = (float)row[2560 + vh * 128 + lane], x2 = (float)row[2560 + vh * 128 + 64 + lane];
            size_t base = ((size_t)(b * NKV + vh) * 256 + (s >> 3)) * 1024 + (s & 7);
            vt[base + (size_t)lane * 8]        = (bf16)x1;
            vt[base + (size_t)(lane + 64) * 8] = (bf16)x2;
        }
    }
}

// ---------------- flash attention (causal, GQA) ----------------
// BM=128 (4 waves x 32 rows), BN=64; paired q-tiles (p, 15-p) for balance;
// double-buffered async K/V staging; one barrier per tile.
__global__ __launch_bounds__(256, 1) void flash(const bf16* __restrict__ qg,
                                                const bf16* __restrict__ kg,
                                                const bf16* __restrict__ vg,
                                                bf16* __restrict__ attn) {
    const int p = blockIdx.x, h = blockIdx.y, b = blockIdx.z;
    const int kvh = h >> 2;
    const bf16* qh = qg + (size_t)(b * NH + h) * S_LEN * HD;
    const bf16* kh = kg + (size_t)(b * NKV + kvh) * (16 * 16384);
    const bf16* vh = vg + (size_t)(b * NKV + kvh) * (256 * 1024);
    __shared__ __align__(16) bf16 Ks[2][16 * 512];   // [dchunk][klocal][8]
    __shared__ __align__(16) bf16 Vs[2][8 * 1024];   // [kchunk][d][8]
    __shared__ __align__(16) bf16 Ps[4][32 * 72];
    const int t = threadIdx.x, lane = t & 63, w = t >> 6, lr = lane & 15, quad = lane >> 4;
    bf16* psw = &Ps[w][0];
    const float scale = 0.08838834764831845f;

    for (int pass = 0; pass < 2; ++pass) {
        const int qt = pass ? (15 - p) : p;
        const int ntile = 2 * qt + 2;
        const int row0 = qt * 128 + w * 32;
        bf16x8 qf[2][4];
#pragma unroll
        for (int mg = 0; mg < 2; mg++)
#pragma unroll
            for (int c = 0; c < 4; c++)
                qf[mg][c] = *(const bf16x8*)(qh + (size_t)(row0 + mg * 16 + lr) * HD + c * 32 + quad * 8);
        f32x4 o[2][8];
#pragma unroll
        for (int mg = 0; mg < 2; mg++)
#pragma unroll
            for (int j = 0; j < 8; j++) o[mg][j] = (f32x4){0.f, 0.f, 0.f, 0.f};
        float mi[2][4], li[2][4];
#pragma unroll
        for (int mg = 0; mg < 2; mg++)
#pragma unroll
            for (int r = 0; r < 4; r++) { mi[mg][r] = -INFINITY; li[mg][r] = 0.f; }

        // preamble: prefetch tile 0 into buf 0
#pragma unroll
        for (int i = 0; i < 4; i++) {
            const int dc = w * 4 + i;
            gl_lds16(kh + (size_t)dc * 16384 + (size_t)lane * 8, &Ks[0][dc * 512]);
        }
#pragma unroll
        for (int i = 0; i < 4; i++) {
            const int seg = w * 4 + i;
            gl_lds16(vh + (size_t)seg * 512 + (size_t)lane * 8, &Vs[0][seg * 512]);
        }
        __syncthreads();
        int cur = 0;
        for (int kt = 0; kt < ntile; ++kt) {
            const int kbase = kt * 64;
            if (kt + 1 < ntile) {  // async prefetch next tile into other buffer
                const int nb = kbase + 64, bb = cur ^ 1;
#pragma unroll
                for (int i = 0; i < 4; i++) {
                    const int dc = w * 4 + i;
                    gl_lds16(kh + (size_t)dc * 16384 + (size_t)(nb + lane) * 8, &Ks[bb][dc * 512]);
                }
                const bf16* vsrc = vh + (size_t)nb * 128;
#pragma unroll
                for (int i = 0; i < 4; i++) {
                    const int seg = w * 4 + i;
                    gl_lds16(vsrc + (size_t)seg * 512 + (size_t)lane * 8, &Vs[bb][seg * 512]);
                }
            }
            // ---- QK^T (each kf feeds both m-groups) ----
            f32x4 sacc[2][4];
#pragma unroll
            for (int mg = 0; mg < 2; mg++)
#pragma unroll
                for (int n = 0; n < 4; n++) sacc[mg][n] = (f32x4){0.f, 0.f, 0.f, 0.f};
#pragma unroll
            for (int n = 0; n < 4; n++)
#pragma unroll
                for (int c = 0; c < 4; c++) {
                    bf16x8 kf = *(const bf16x8*)&Ks[cur][(c * 4 + quad) * 512 + (n * 16 + lr) * 8];
                    sacc[0][n] = __builtin_amdgcn_mfma_f32_16x16x32_bf16(qf[0][c], kf, sacc[0][n], 0, 0, 0);
                    sacc[1][n] = __builtin_amdgcn_mfma_f32_16x16x32_bf16(qf[1][c], kf, sacc[1][n], 0, 0, 0);
                }
            // ---- online softmax ----
            const bool diag = (kt >= 2 * qt);
#pragma unroll
            for (int mg = 0; mg < 2; mg++) {
#pragma unroll
                for (int r = 0; r < 4; r++) {
                    const int qrow = row0 + mg * 16 + quad * 4 + r;
                    float v0 = sacc[mg][0][r] * scale;
                    float v1 = sacc[mg][1][r] * scale;
                    float v2 = sacc[mg][2][r] * scale;
                    float v3 = sacc[mg][3][r] * scale;
                    if (diag) {
                        v0 = (kbase + 0 + lr <= qrow) ? v0 : -1e30f;
                        v1 = (kbase + 16 + lr <= qrow) ? v1 : -1e30f;
                        v2 = (kbase + 32 + lr <= qrow) ? v2 : -1e30f;
                        v3 = (kbase + 48 + lr <= qrow) ? v3 : -1e30f;
                    }
                    float rmax = fmaxf(fmaxf(v0, v1), fmaxf(v2, v3));
#pragma unroll
                    for (int m = 1; m < 16; m <<= 1) rmax = fmaxf(rmax, __shfl_xor(rmax, m));
                    const float mnew = fmaxf(mi[mg][r], rmax);
                    const float alpha = __expf(mi[mg][r] - mnew);
                    const float p0 = __expf(v0 - mnew), p1 = __expf(v1 - mnew);
                    const float p2 = __expf(v2 - mnew), p3 = __expf(v3 - mnew);
                    float ps = (p0 + p1) + (p2 + p3);
#pragma unroll
                    for (int m = 1; m < 16; m <<= 1) ps += __shfl_xor(ps, m);
                    li[mg][r] = li[mg][r] * alpha + ps;
                    mi[mg][r] = mnew;
#pragma unroll
                    for (int j = 0; j < 8; j++) o[mg][j][r] *= alpha;
                    const int prow = (mg * 16 + quad * 4 + r) * 72;
                    psw[prow + lr]      = (bf16)p0;
                    psw[prow + 16 + lr] = (bf16)p1;
                    psw[prow + 32 + lr] = (bf16)p2;
                    psw[prow + 48 + lr] = (bf16)p3;
                }
            }
            // ---- PV (wave-local Ps round-trip, no barrier; vf feeds both m-groups) ----
            bf16x8 pf[2][2];
#pragma unroll
            for (int mg = 0; mg < 2; mg++)
#pragma unroll
                for (int k2 = 0; k2 < 2; k2++)
                    pf[mg][k2] = *(const bf16x8*)&psw[(mg * 16 + lr) * 72 + k2 * 32 + quad * 8];
#pragma unroll
            for (int j = 0; j < 8; j++)
#pragma unroll
                for (int k2 = 0; k2 < 2; k2++) {
                    bf16x8 vf = *(const bf16x8*)&Vs[cur][(k2 * 4 + quad) * 1024 + (j * 16 + lr) * 8];
                    o[0][j] = __builtin_amdgcn_mfma_f32_16x16x32_bf16(pf[0][k2], vf, o[0][j], 0, 0, 0);
                    o[1][j] = __builtin_amdgcn_mfma_f32_16x16x32_bf16(pf[1][k2], vf, o[1][j], 0, 0, 0);
                }
            __syncthreads();  // buffer handoff: readers done + next-tile loads drained
            cur ^= 1;
        }
        // epilogue
#pragma unroll
        for (int mg = 0; mg < 2; mg++)
#pragma unroll
            for (int j = 0; j < 8; j++)
#pragma unroll
                for (int r = 0; r < 4; r++) {
                    const int qrow = row0 + mg * 16 + quad * 4 + r;
                    attn[((size_t)(b * S_LEN) + qrow) * (NH * HD) + h * HD + j * 16 + lr] =
                        (bf16)(o[mg][j][r] / li[mg][r]);
                }
    }
}

extern "C" void kernel_launch(void* const* d_in, const int* in_sizes, int n_in,
                              void* d_out, int out_size, void* d_ws, size_t ws_size,
                              hipStream_t stream) {
    (void)in_sizes; (void)n_in; (void)out_size; (void)ws_size;
    const float* hs  = (const float*)d_in[0];
    const float* wq  = (const float*)d_in[1];
    const float* wk  = (const float*)d_in[2];
    const float* wv  = (const float*)d_in[3];
    const float* wo  = (const float*)d_in[4];
    const float* qnw = (const float*)d_in[5];
    const float* knw = (const float*)d_in[6];
    float* out = (float*)d_out;

    char* ws = (char*)d_ws;
    size_t off = 0;
    auto alloc = [&](size_t bytes) {
        void* p = ws + off;
        off += (bytes + 255) & ~(size_t)255;
        return p;
    };
    bf16* hs_bf   = (bf16*)alloc((size_t)4096 * 2048 * 2);
    bf16* wqkv_bf = (bf16*)alloc((size_t)3072 * 2048 * 2);
    bf16* wo_bf   = (bf16*)alloc((size_t)2048 * 2048 * 2);
    bf16* qkv_bf  = (bf16*)alloc((size_t)4096 * 3072 * 2);
    bf16* q_bf    = (bf16*)alloc((size_t)B_DIM * NH * S_LEN * HD * 2);
    bf16* k_bf    = (bf16*)alloc((size_t)B_DIM * NKV * S_LEN * HD * 2);
    bf16* vt_bf   = (bf16*)alloc((size_t)B_DIM * NKV * S_LEN * HD * 2);
    bf16* at_bf   = (bf16*)alloc((size_t)4096 * 2048 * 2);

    cast_kernel<<<8192, 256, 0, stream>>>(hs, hs_bf, 2097152);
    cast_kernel<<<4096, 256, 0, stream>>>(wq, wqkv_bf, 1048576);
    cast_kernel<<<1024, 256, 0, stream>>>(wk, wqkv_bf + 4194304, 262144);
    cast_kernel<<<1024, 256, 0, stream>>>(wv, wqkv_bf + 5242880, 262144);
    cast_kernel<<<4096, 256, 0, stream>>>(wo, wo_bf, 1048576);

    gemm_bt<bf16><<<dim3(32, 24), 256, 0, stream>>>(hs_bf, wqkv_bf, qkv_bf, 4096, 3072, 2048);
    rope_rms<<<4096, 256, 0, stream>>>(qkv_bf, qnw, knw, q_bf, k_bf, vt_bf);
    flash<<<dim3(8, 16, 2), 256, 0, stream>>>(q_bf, k_bf, vt_bf, at_bf);
    gemm_bt<float><<<dim3(32, 16), 256, 0, stream>>>(at_bf, wo_bf, out, 4096, 2048, 2048);
}

// Round 3
// 352.332 us; speedup vs baseline: 1.5561x; 1.1723x over previous
//
#include <hip/hip_runtime.h>
#include <math.h>

typedef __bf16 bf16;
typedef __bf16 bf16x8 __attribute__((ext_vector_type(8)));
typedef __bf16 bf16x4 __attribute__((ext_vector_type(4)));
typedef float f32x4 __attribute__((ext_vector_type(4)));

#define B_DIM 2
#define S_LEN 2048
#define H_DIM 2048
#define NH 16
#define NKV 4
#define HD 128

// async global->LDS, 16B per lane; LDS dest = wave-uniform base (HW adds lane*16)
__device__ __forceinline__ void gl_lds16(const void* g, void* l) {
    __builtin_amdgcn_global_load_lds(
        (const __attribute__((address_space(1))) unsigned int*)g,
        (__attribute__((address_space(3))) unsigned int*)l, 16, 0, 0);
}

// ---------------- cast fp32 -> bf16 (vectorized x4) ----------------
__global__ void cast_kernel(const float* __restrict__ src, bf16* __restrict__ dst, int n4) {
    int i = blockIdx.x * 256 + threadIdx.x;
    if (i >= n4) return;
    float4 f = ((const float4*)src)[i];
    bf16x4 o = { (bf16)f.x, (bf16)f.y, (bf16)f.z, (bf16)f.w };
    *(bf16x4*)(dst + (size_t)i * 4) = o;
}

// ---------------- bt-GEMM: C[M][N] = A[M][K] * Bt[N][K]^T ----------------
template <typename OutT>
__global__ __launch_bounds__(256) void gemm_bt(const bf16* __restrict__ A,
                                               const bf16* __restrict__ Bt,
                                               OutT* __restrict__ C,
                                               int M, int N, int K) {
    __shared__ __align__(16) bf16 As[128 * 32];
    __shared__ __align__(16) bf16 Bs[128 * 32];
    const int t = threadIdx.x;
    const int lane = t & 63, w = t >> 6;
    const int wm = (w & 1) * 64, wn = (w >> 1) * 64;
    const int lr = lane & 15, quad = lane >> 4;
    const int m0 = blockIdx.x * 128, n0 = blockIdx.y * 128;
    const int lrow = lane >> 2, lk = (lane & 3) * 8;
    f32x4 acc[4][4];
#pragma unroll
    for (int i = 0; i < 4; i++)
#pragma unroll
        for (int j = 0; j < 4; j++) acc[i][j] = (f32x4){0.f, 0.f, 0.f, 0.f};

    for (int k0 = 0; k0 < K; k0 += 32) {
        __syncthreads();
#pragma unroll
        for (int i = 0; i < 2; i++) {
            const int r0 = i * 64 + w * 16;
            gl_lds16(A + (size_t)(m0 + r0 + lrow) * K + k0 + lk, &As[r0 * 32]);
            gl_lds16(Bt + (size_t)(n0 + r0 + lrow) * K + k0 + lk, &Bs[r0 * 32]);
        }
        __syncthreads();
        bf16x8 af[4], bfr[4];
#pragma unroll
        for (int i = 0; i < 4; i++) af[i] = *(const bf16x8*)&As[(wm + i * 16 + lr) * 32 + quad * 8];
#pragma unroll
        for (int j = 0; j < 4; j++) bfr[j] = *(const bf16x8*)&Bs[(wn + j * 16 + lr) * 32 + quad * 8];
#pragma unroll
        for (int i = 0; i < 4; i++)
#pragma unroll
            for (int j = 0; j < 4; j++)
                acc[i][j] = __builtin_amdgcn_mfma_f32_16x16x32_bf16(af[i], bfr[j], acc[i][j], 0, 0, 0);
    }
#pragma unroll
    for (int i = 0; i < 4; i++) {
        int m = m0 + wm + i * 16 + quad * 4;
#pragma unroll
        for (int j = 0; j < 4; j++) {
            int n = n0 + wn + j * 16 + lr;
#pragma unroll
            for (int r = 0; r < 4; r++)
                C[(size_t)(m + r) * N + n] = (OutT)acc[i][j][r];
        }
    }
}

// ---------------- RoPE + RMSNorm; K and V written in MFMA-tiled layouts ----------------
// K: [(b,kvh)][dchunk=d>>3 (16)][s (2048)][d&7 (8)]
// V: [(b,kvh)][schunk=s>>3 (256)][d (128)][s&7 (8)]
__global__ __launch_bounds__(256) void rope_rms(const bf16* __restrict__ qkv,
                                                const float* __restrict__ qw,
                                                const float* __restrict__ kw,
                                                bf16* __restrict__ qb,
                                                bf16* __restrict__ kb,
                                                bf16* __restrict__ vt) {
    const int tok = blockIdx.x;
    const int b = tok >> 11, s = tok & (S_LEN - 1);
    const int lane = threadIdx.x & 63, w = threadIdx.x >> 6;
    const bf16* row = qkv + (size_t)tok * 3072;
    const float inv = expf(-(float)lane * (9.210340371976184f / 64.f));
    const float ang = (float)s * inv;
    float s_, c_;
    sincosf(ang, &s_, &c_);
    const float wq1 = qw[lane], wq2 = qw[lane + 64];
    const float wk1 = kw[lane], wk2 = kw[lane + 64];
    for (int u = w; u < 24; u += 4) {
        if (u < 16) {  // Q head: row-major [b,h][s][d]
            const float x1 = (float)row[u * 128 + lane], x2 = (float)row[u * 128 + 64 + lane];
            float y1 = x1 * c_ - x2 * s_;
            float y2 = x2 * c_ + x1 * s_;
            float ss = y1 * y1 + y2 * y2;
#pragma unroll
            for (int m = 1; m < 64; m <<= 1) ss += __shfl_xor(ss, m);
            const float r = rsqrtf(ss * (1.f / 128.f) + 1e-6f);
            size_t o = ((size_t)(b * NH + u) * S_LEN + s) * HD;
            qb[o + lane]      = (bf16)(y1 * r * wq1);
            qb[o + 64 + lane] = (bf16)(y2 * r * wq2);
        } else if (u < 20) {  // K head: tiled
            const int kh = u - 16;
            const float x1 = (float)row[2048 + kh * 128 + lane], x2 = (float)row[2048 + kh * 128 + 64 + lane];
            float y1 = x1 * c_ - x2 * s_;
            float y2 = x2 * c_ + x1 * s_;
            float ss = y1 * y1 + y2 * y2;
#pragma unroll
            for (int m = 1; m < 64; m <<= 1) ss += __shfl_xor(ss, m);
            const float r = rsqrtf(ss * (1.f / 128.f) + 1e-6f);
            size_t base = (size_t)(b * NKV + kh) * 16 * 16384;
            kb[base + (size_t)(lane >> 3) * 16384 + s * 8 + (lane & 7)]       = (bf16)(y1 * r * wk1);
            kb[base + (size_t)(8 + (lane >> 3)) * 16384 + s * 8 + (lane & 7)] = (bf16)(y2 * r * wk2);
        } else {  // V head: tiled cast
            const int vh = u - 20;
            const float x1 = (float)row[2560 + vh * 128 + lane], x2 = (float)row[2560 + vh * 128 + 64 + lane];
            size_t base = ((size_t)(b * NKV + vh) * 256 + (s >> 3)) * 1024 + (s & 7);
            vt[base + (size_t)lane * 8]        = (bf16)x1;
            vt[base + (size_t)(lane + 64) * 8] = (bf16)x2;
        }
    }
}

// ---------------- flash attention v3 (causal, GQA) ----------------
// BM=64 (2 waves x 32 rows, mg=2), BN=64. Single-buffered K/V LDS (43 KB ->
// 3 blocks/CU); fixed-max softmax (scores <= sqrt(128) by Cauchy-Schwarz);
// row-sum l accumulated via MFMA with a ones-extended V tile (no shuffles).
__global__ __launch_bounds__(128, 2) void flash(const bf16* __restrict__ qg,
                                                const bf16* __restrict__ kg,
                                                const bf16* __restrict__ vg,
                                                bf16* __restrict__ attn) {
    const int idx = blockIdx.x;
    const int qt = 31 - (idx >> 5);       // big blocks launch first
    const int hb = idx & 31;
    const int h = hb & 15, b = hb >> 4;
    const int kvh = h >> 2;
    const bf16* qh = qg + (size_t)(b * NH + h) * S_LEN * HD;
    const bf16* kh = kg + (size_t)(b * NKV + kvh) * (16 * 16384);
    const bf16* vh = vg + (size_t)(b * NKV + kvh) * (256 * 1024);
    __shared__ __align__(16) bf16 Ks[16 * 512];    // [dchunk16][key64][8]   16 KB
    __shared__ __align__(16) bf16 Vs[8 * 1152];    // [kchunk8][d144][8]     18 KB (d=128..143 = ones)
    __shared__ __align__(16) bf16 Ps[2][32 * 72];  // per-wave P round-trip   9 KB
    const int t = threadIdx.x, lane = t & 63, w = t >> 6, lr = lane & 15, quad = lane >> 4;
    bf16* psw = Ps[w];
    {   // ones region for the l-sum MFMA trick (never overwritten by staging)
        const bf16 one = (bf16)1.0f;
        bf16x8 one8 = {one, one, one, one, one, one, one, one};
        *(bf16x8*)&Vs[(t >> 4) * 1152 + 1024 + (t & 15) * 8] = one8;
    }
    const int row0 = qt * 64 + w * 32;
    bf16x8 qf[2][4];
#pragma unroll
    for (int mg = 0; mg < 2; mg++)
#pragma unroll
        for (int c = 0; c < 4; c++)
            qf[mg][c] = *(const bf16x8*)(qh + (size_t)(row0 + mg * 16 + lr) * HD + c * 32 + quad * 8);
    f32x4 o[2][8];
    f32x4 lacc[2];
#pragma unroll
    for (int mg = 0; mg < 2; mg++) {
        lacc[mg] = (f32x4){0.f, 0.f, 0.f, 0.f};
#pragma unroll
        for (int j = 0; j < 8; j++) o[mg][j] = (f32x4){0.f, 0.f, 0.f, 0.f};
    }
    const float C1 = 0.12751744f;    // (1/sqrt(128)) * log2(e)
    const float C2 = -17.3123405f;   // -12 * log2(e)   (fixed max M=12 > sqrt(128))
    const int ntile = qt + 1;

    for (int kt = 0; kt < ntile; ++kt) {
        const int kbase = kt * 64;
        __syncthreads();  // previous tile's LDS reads complete
#pragma unroll
        for (int i = 0; i < 8; i++) {  // K tile: 16 dchunks, 8 per wave
            const int dc = w * 8 + i;
            gl_lds16(kh + (size_t)dc * 16384 + (size_t)kbase * 8 + lane * 8, &Ks[dc * 512]);
        }
#pragma unroll
        for (int i = 0; i < 4; i++) {  // V tile: 8 schunks, 4 per wave, 2 loads each
            const int c = w * 4 + i;
            const bf16* src = vh + ((size_t)(kbase >> 3) + c) * 1024 + lane * 8;
            gl_lds16(src, &Vs[c * 1152]);
            gl_lds16(src + 512, &Vs[c * 1152 + 512]);
        }
        __syncthreads();  // staging visible
        // ---- QK^T ----
        f32x4 sacc[2][4];
#pragma unroll
        for (int mg = 0; mg < 2; mg++)
#pragma unroll
            for (int n = 0; n < 4; n++) sacc[mg][n] = (f32x4){0.f, 0.f, 0.f, 0.f};
#pragma unroll
        for (int n = 0; n < 4; n++)
#pragma unroll
            for (int c = 0; c < 4; c++) {
                bf16x8 kf = *(const bf16x8*)&Ks[(c * 4 + quad) * 512 + (n * 16 + lr) * 8];
                sacc[0][n] = __builtin_amdgcn_mfma_f32_16x16x32_bf16(qf[0][c], kf, sacc[0][n], 0, 0, 0);
                sacc[1][n] = __builtin_amdgcn_mfma_f32_16x16x32_bf16(qf[1][c], kf, sacc[1][n], 0, 0, 0);
            }
        // ---- fixed-max softmax: p = 2^(s*C1 + C2), no reductions ----
        const bool diag = (kt == qt);
#pragma unroll
        for (int mg = 0; mg < 2; mg++)
#pragma unroll
            for (int n = 0; n < 4; n++)
#pragma unroll
                for (int r = 0; r < 4; r++) {
                    float e = exp2f(fmaf(sacc[mg][n][r], C1, C2));
                    if (diag) {
                        const int key = kbase + n * 16 + lr;
                        const int qrow = row0 + mg * 16 + quad * 4 + r;
                        e = (key <= qrow) ? e : 0.f;
                    }
                    psw[(mg * 16 + quad * 4 + r) * 72 + n * 16 + lr] = (bf16)e;
                }
        // ---- PV + l (wave-local round-trip, no barrier) ----
        bf16x8 pf[2][2];
#pragma unroll
        for (int mg = 0; mg < 2; mg++)
#pragma unroll
            for (int k2 = 0; k2 < 2; k2++)
                pf[mg][k2] = *(const bf16x8*)&psw[(mg * 16 + lr) * 72 + k2 * 32 + quad * 8];
#pragma unroll
        for (int k2 = 0; k2 < 2; k2++) {
#pragma unroll
            for (int j = 0; j < 8; j++) {
                bf16x8 vf = *(const bf16x8*)&Vs[(k2 * 4 + quad) * 1152 + (j * 16 + lr) * 8];
                o[0][j] = __builtin_amdgcn_mfma_f32_16x16x32_bf16(pf[0][k2], vf, o[0][j], 0, 0, 0);
                o[1][j] = __builtin_amdgcn_mfma_f32_16x16x32_bf16(pf[1][k2], vf, o[1][j], 0, 0, 0);
            }
            bf16x8 vone = *(const bf16x8*)&Vs[(k2 * 4 + quad) * 1152 + (128 + lr) * 8];
            lacc[0] = __builtin_amdgcn_mfma_f32_16x16x32_bf16(pf[0][k2], vone, lacc[0], 0, 0, 0);
            lacc[1] = __builtin_amdgcn_mfma_f32_16x16x32_bf16(pf[1][k2], vone, lacc[1], 0, 0, 0);
        }
    }
    // epilogue
#pragma unroll
    for (int mg = 0; mg < 2; mg++) {
        float inv[4];
#pragma unroll
        for (int r = 0; r < 4; r++) inv[r] = 1.0f / lacc[mg][r];
#pragma unroll
        for (int j = 0; j < 8; j++)
#pragma unroll
            for (int r = 0; r < 4; r++) {
                const int qrow = row0 + mg * 16 + quad * 4 + r;
                attn[((size_t)(b * S_LEN) + qrow) * (NH * HD) + h * HD + j * 16 + lr] =
                    (bf16)(o[mg][j][r] * inv[r]);
            }
    }
}

extern "C" void kernel_launch(void* const* d_in, const int* in_sizes, int n_in,
                              void* d_out, int out_size, void* d_ws, size_t ws_size,
                              hipStream_t stream) {
    (void)in_sizes; (void)n_in; (void)out_size; (void)ws_size;
    const float* hs  = (const float*)d_in[0];
    const float* wq  = (const float*)d_in[1];
    const float* wk  = (const float*)d_in[2];
    const float* wv  = (const float*)d_in[3];
    const float* wo  = (const float*)d_in[4];
    const float* qnw = (const float*)d_in[5];
    const float* knw = (const float*)d_in[6];
    float* out = (float*)d_out;

    char* ws = (char*)d_ws;
    size_t off = 0;
    auto alloc = [&](size_t bytes) {
        void* p = ws + off;
        off += (bytes + 255) & ~(size_t)255;
        return p;
    };
    bf16* hs_bf   = (bf16*)alloc((size_t)4096 * 2048 * 2);
    bf16* wqkv_bf = (bf16*)alloc((size_t)3072 * 2048 * 2);
    bf16* wo_bf   = (bf16*)alloc((size_t)2048 * 2048 * 2);
    bf16* qkv_bf  = (bf16*)alloc((size_t)4096 * 3072 * 2);
    bf16* q_bf    = (bf16*)alloc((size_t)B_DIM * NH * S_LEN * HD * 2);
    bf16* k_bf    = (bf16*)alloc((size_t)B_DIM * NKV * S_LEN * HD * 2);
    bf16* vt_bf   = (bf16*)alloc((size_t)B_DIM * NKV * S_LEN * HD * 2);
    bf16* at_bf   = (bf16*)alloc((size_t)4096 * 2048 * 2);

    cast_kernel<<<8192, 256, 0, stream>>>(hs, hs_bf, 2097152);
    cast_kernel<<<4096, 256, 0, stream>>>(wq, wqkv_bf, 1048576);
    cast_kernel<<<1024, 256, 0, stream>>>(wk, wqkv_bf + 4194304, 262144);
    cast_kernel<<<1024, 256, 0, stream>>>(wv, wqkv_bf + 5242880, 262144);
    cast_kernel<<<4096, 256, 0, stream>>>(wo, wo_bf, 1048576);

    gemm_bt<bf16><<<dim3(32, 24), 256, 0, stream>>>(hs_bf, wqkv_bf, qkv_bf, 4096, 3072, 2048);
    rope_rms<<<4096, 256, 0, stream>>>(qkv_bf, qnw, knw, q_bf, k_bf, vt_bf);
    flash<<<dim3(1024), 128, 0, stream>>>(q_bf, k_bf, vt_bf, at_bf);
    gemm_bt<float><<<dim3(32, 16), 256, 0, stream>>>(at_bf, wo_bf, out, 4096, 2048, 2048);
}

// Round 4
// 337.901 us; speedup vs baseline: 1.6225x; 1.0427x over previous
//
#include <hip/hip_runtime.h>
#include <math.h>

typedef __bf16 bf16;
typedef __bf16 bf16x8 __attribute__((ext_vector_type(8)));
typedef __bf16 bf16x4 __attribute__((ext_vector_type(4)));
typedef float f32x4 __attribute__((ext_vector_type(4)));

#define B_DIM 2
#define S_LEN 2048
#define H_DIM 2048
#define NH 16
#define NKV 4
#define HD 128

// async global->LDS, 16B per lane; LDS dest = wave-uniform base (HW adds lane*16)
__device__ __forceinline__ void gl_lds16(const void* g, void* l) {
    __builtin_amdgcn_global_load_lds(
        (const __attribute__((address_space(1))) unsigned int*)g,
        (__attribute__((address_space(3))) unsigned int*)l, 16, 0, 0);
}

// ---------------- merged cast fp32 -> bf16 for all 5 inputs ----------------
// dst regions are contiguous in ws: [hs 2097152 f4][wq 1048576][wk 262144][wv 262144][wo 1048576]
__global__ __launch_bounds__(256) void cast_all(const float* __restrict__ s0,
                                                const float* __restrict__ s1,
                                                const float* __restrict__ s2,
                                                const float* __restrict__ s3,
                                                const float* __restrict__ s4,
                                                bf16* __restrict__ dst) {
    const int i = blockIdx.x * 256 + threadIdx.x;  // f4 index, < 4718592
    const float* src;
    int off;
    if (i < 2097152)      { src = s0; off = 0; }
    else if (i < 3145728) { src = s1; off = 2097152; }
    else if (i < 3407872) { src = s2; off = 3145728; }
    else if (i < 3670016) { src = s3; off = 3407872; }
    else                  { src = s4; off = 3670016; }
    float4 f = ((const float4*)src)[i - off];
    bf16x4 o = { (bf16)f.x, (bf16)f.y, (bf16)f.z, (bf16)f.w };
    *(bf16x4*)(dst + (size_t)i * 4) = o;
}

// ---------------- bt-GEMM: C[M][N] = A[M][K] * Bt[N][K]^T ----------------
template <typename OutT>
__global__ __launch_bounds__(256) void gemm_bt(const bf16* __restrict__ A,
                                               const bf16* __restrict__ Bt,
                                               OutT* __restrict__ C,
                                               int M, int N, int K) {
    __shared__ __align__(16) bf16 As[128 * 32];
    __shared__ __align__(16) bf16 Bs[128 * 32];
    const int t = threadIdx.x;
    const int lane = t & 63, w = t >> 6;
    const int wm = (w & 1) * 64, wn = (w >> 1) * 64;
    const int lr = lane & 15, quad = lane >> 4;
    const int m0 = blockIdx.x * 128, n0 = blockIdx.y * 128;
    const int lrow = lane >> 2, lk = (lane & 3) * 8;
    f32x4 acc[4][4];
#pragma unroll
    for (int i = 0; i < 4; i++)
#pragma unroll
        for (int j = 0; j < 4; j++) acc[i][j] = (f32x4){0.f, 0.f, 0.f, 0.f};

    for (int k0 = 0; k0 < K; k0 += 32) {
        __syncthreads();
#pragma unroll
        for (int i = 0; i < 2; i++) {
            const int r0 = i * 64 + w * 16;
            gl_lds16(A + (size_t)(m0 + r0 + lrow) * K + k0 + lk, &As[r0 * 32]);
            gl_lds16(Bt + (size_t)(n0 + r0 + lrow) * K + k0 + lk, &Bs[r0 * 32]);
        }
        __syncthreads();
        bf16x8 af[4], bfr[4];
#pragma unroll
        for (int i = 0; i < 4; i++) af[i] = *(const bf16x8*)&As[(wm + i * 16 + lr) * 32 + quad * 8];
#pragma unroll
        for (int j = 0; j < 4; j++) bfr[j] = *(const bf16x8*)&Bs[(wn + j * 16 + lr) * 32 + quad * 8];
#pragma unroll
        for (int i = 0; i < 4; i++)
#pragma unroll
            for (int j = 0; j < 4; j++)
                acc[i][j] = __builtin_amdgcn_mfma_f32_16x16x32_bf16(af[i], bfr[j], acc[i][j], 0, 0, 0);
    }
#pragma unroll
    for (int i = 0; i < 4; i++) {
        int m = m0 + wm + i * 16 + quad * 4;
#pragma unroll
        for (int j = 0; j < 4; j++) {
            int n = n0 + wn + j * 16 + lr;
#pragma unroll
            for (int r = 0; r < 4; r++)
                C[(size_t)(m + r) * N + n] = (OutT)acc[i][j][r];
        }
    }
}

// ---------------- RoPE + RMSNorm; K and V written in MFMA-tiled layouts ----------------
// K: [(b,kvh)][dchunk=d>>3 (16)][s (2048)][d&7 (8)]
// V: [(b,kvh)][schunk=s>>3 (256)][d (128)][s&7 (8)]
__global__ __launch_bounds__(256) void rope_rms(const bf16* __restrict__ qkv,
                                                const float* __restrict__ qw,
                                                const float* __restrict__ kw,
                                                bf16* __restrict__ qb,
                                                bf16* __restrict__ kb,
                                                bf16* __restrict__ vt) {
    const int tok = blockIdx.x;
    const int b = tok >> 11, s = tok & (S_LEN - 1);
    const int lane = threadIdx.x & 63, w = threadIdx.x >> 6;
    const bf16* row = qkv + (size_t)tok * 3072;
    const float inv = expf(-(float)lane * (9.210340371976184f / 64.f));
    const float ang = (float)s * inv;
    float s_, c_;
    sincosf(ang, &s_, &c_);
    const float wq1 = qw[lane], wq2 = qw[lane + 64];
    const float wk1 = kw[lane], wk2 = kw[lane + 64];
    for (int u = w; u < 24; u += 4) {
        if (u < 16) {  // Q head: row-major [b,h][s][d]
            const float x1 = (float)row[u * 128 + lane], x2 = (float)row[u * 128 + 64 + lane];
            float y1 = x1 * c_ - x2 * s_;
            float y2 = x2 * c_ + x1 * s_;
            float ss = y1 * y1 + y2 * y2;
#pragma unroll
            for (int m = 1; m < 64; m <<= 1) ss += __shfl_xor(ss, m);
            const float r = rsqrtf(ss * (1.f / 128.f) + 1e-6f);
            size_t o = ((size_t)(b * NH + u) * S_LEN + s) * HD;
            qb[o + lane]      = (bf16)(y1 * r * wq1);
            qb[o + 64 + lane] = (bf16)(y2 * r * wq2);
        } else if (u < 20) {  // K head: tiled
            const int kh = u - 16;
            const float x1 = (float)row[2048 + kh * 128 + lane], x2 = (float)row[2048 + kh * 128 + 64 + lane];
            float y1 = x1 * c_ - x2 * s_;
            float y2 = x2 * c_ + x1 * s_;
            float ss = y1 * y1 + y2 * y2;
#pragma unroll
            for (int m = 1; m < 64; m <<= 1) ss += __shfl_xor(ss, m);
            const float r = rsqrtf(ss * (1.f / 128.f) + 1e-6f);
            size_t base = (size_t)(b * NKV + kh) * 16 * 16384;
            kb[base + (size_t)(lane >> 3) * 16384 + s * 8 + (lane & 7)]       = (bf16)(y1 * r * wk1);
            kb[base + (size_t)(8 + (lane >> 3)) * 16384 + s * 8 + (lane & 7)] = (bf16)(y2 * r * wk2);
        } else {  // V head: tiled cast
            const int vh = u - 20;
            const float x1 = (float)row[2560 + vh * 128 + lane], x2 = (float)row[2560 + vh * 128 + 64 + lane];
            size_t base = ((size_t)(b * NKV + vh) * 256 + (s >> 3)) * 1024 + (s & 7);
            vt[base + (size_t)lane * 8]        = (bf16)x1;
            vt[base + (size_t)(lane + 64) * 8] = (bf16)x2;
        }
    }
}

// ---------------- flash attention v4 (causal, GQA) ----------------
// BM=128 (4 waves x 32 rows, mg=2), BN=64. Single-buffered K/V LDS (52 KB);
// 512 blocks -> entire grid co-resident (zero tail). Fixed-max softmax
// (scores <= sqrt(128)); row-sum l via MFMA with ones-extended V tile.
__global__ __launch_bounds__(256, 2) void flash(const bf16* __restrict__ qg,
                                                const bf16* __restrict__ kg,
                                                const bf16* __restrict__ vg,
                                                bf16* __restrict__ attn) {
    const int idx = blockIdx.x;
    const int qt = 15 - (idx >> 5);       // big blocks launch first
    const int hb = idx & 31;
    const int h = hb & 15, b = hb >> 4;
    const int kvh = h >> 2;
    const bf16* qh = qg + (size_t)(b * NH + h) * S_LEN * HD;
    const bf16* kh = kg + (size_t)(b * NKV + kvh) * (16 * 16384);
    const bf16* vh = vg + (size_t)(b * NKV + kvh) * (256 * 1024);
    __shared__ __align__(16) bf16 Ks[16 * 512];    // [dchunk16][key64][8]   16 KB
    __shared__ __align__(16) bf16 Vs[8 * 1152];    // [kchunk8][d144][8]     18 KB (d=128..143 = ones)
    __shared__ __align__(16) bf16 Ps[4][32 * 72];  // per-wave P round-trip  18 KB
    const int t = threadIdx.x, lane = t & 63, w = t >> 6, lr = lane & 15, quad = lane >> 4;
    bf16* psw = Ps[w];
    if (t < 128) {  // ones region for the l-sum MFMA trick (never overwritten)
        const bf16 one = (bf16)1.0f;
        bf16x8 one8 = {one, one, one, one, one, one, one, one};
        *(bf16x8*)&Vs[(t >> 4) * 1152 + 1024 + (t & 15) * 8] = one8;
    }
    const int row0 = qt * 128 + w * 32;
    bf16x8 qf[2][4];
#pragma unroll
    for (int mg = 0; mg < 2; mg++)
#pragma unroll
        for (int c = 0; c < 4; c++)
            qf[mg][c] = *(const bf16x8*)(qh + (size_t)(row0 + mg * 16 + lr) * HD + c * 32 + quad * 8);
    f32x4 o[2][8];
    f32x4 lacc[2];
#pragma unroll
    for (int mg = 0; mg < 2; mg++) {
        lacc[mg] = (f32x4){0.f, 0.f, 0.f, 0.f};
#pragma unroll
        for (int j = 0; j < 8; j++) o[mg][j] = (f32x4){0.f, 0.f, 0.f, 0.f};
    }
    const float C1 = 0.12751744f;    // (1/sqrt(128)) * log2(e)
    const float C2 = -17.3123405f;   // -12 * log2(e)   (fixed max M=12 > sqrt(128))
    const int ntile = 2 * qt + 2;

    for (int kt = 0; kt < ntile; ++kt) {
        const int kbase = kt * 64;
        __syncthreads();  // previous tile's LDS reads complete
#pragma unroll
        for (int i = 0; i < 4; i++) {  // K tile: 16 dchunks, 4 per wave
            const int dc = w * 4 + i;
            gl_lds16(kh + (size_t)dc * 16384 + (size_t)kbase * 8 + lane * 8, &Ks[dc * 512]);
        }
#pragma unroll
        for (int i = 0; i < 2; i++) {  // V tile: 8 schunks, 2 per wave, 2 loads each
            const int c = w * 2 + i;
            const bf16* src = vh + ((size_t)(kbase >> 3) + c) * 1024 + lane * 8;
            gl_lds16(src, &Vs[c * 1152]);
            gl_lds16(src + 512, &Vs[c * 1152 + 512]);
        }
        __syncthreads();  // staging visible
        // ---- QK^T ----
        f32x4 sacc[2][4];
#pragma unroll
        for (int mg = 0; mg < 2; mg++)
#pragma unroll
            for (int n = 0; n < 4; n++) sacc[mg][n] = (f32x4){0.f, 0.f, 0.f, 0.f};
#pragma unroll
        for (int n = 0; n < 4; n++)
#pragma unroll
            for (int c = 0; c < 4; c++) {
                bf16x8 kf = *(const bf16x8*)&Ks[(c * 4 + quad) * 512 + (n * 16 + lr) * 8];
                sacc[0][n] = __builtin_amdgcn_mfma_f32_16x16x32_bf16(qf[0][c], kf, sacc[0][n], 0, 0, 0);
                sacc[1][n] = __builtin_amdgcn_mfma_f32_16x16x32_bf16(qf[1][c], kf, sacc[1][n], 0, 0, 0);
            }
        // ---- fixed-max softmax: p = 2^(s*C1 + C2), no reductions ----
        const bool diag = (kt >= 2 * qt);
#pragma unroll
        for (int mg = 0; mg < 2; mg++)
#pragma unroll
            for (int n = 0; n < 4; n++)
#pragma unroll
                for (int r = 0; r < 4; r++) {
                    float e = exp2f(fmaf(sacc[mg][n][r], C1, C2));
                    if (diag) {
                        const int key = kbase + n * 16 + lr;
                        const int qrow = row0 + mg * 16 + quad * 4 + r;
                        e = (key <= qrow) ? e : 0.f;
                    }
                    psw[(mg * 16 + quad * 4 + r) * 72 + n * 16 + lr] = (bf16)e;
                }
        // ---- PV + l (wave-local round-trip, no barrier) ----
        bf16x8 pf[2][2];
#pragma unroll
        for (int mg = 0; mg < 2; mg++)
#pragma unroll
            for (int k2 = 0; k2 < 2; k2++)
                pf[mg][k2] = *(const bf16x8*)&psw[(mg * 16 + lr) * 72 + k2 * 32 + quad * 8];
#pragma unroll
        for (int k2 = 0; k2 < 2; k2++) {
#pragma unroll
            for (int j = 0; j < 8; j++) {
                bf16x8 vf = *(const bf16x8*)&Vs[(k2 * 4 + quad) * 1152 + (j * 16 + lr) * 8];
                o[0][j] = __builtin_amdgcn_mfma_f32_16x16x32_bf16(pf[0][k2], vf, o[0][j], 0, 0, 0);
                o[1][j] = __builtin_amdgcn_mfma_f32_16x16x32_bf16(pf[1][k2], vf, o[1][j], 0, 0, 0);
            }
            bf16x8 vone = *(const bf16x8*)&Vs[(k2 * 4 + quad) * 1152 + (128 + lr) * 8];
            lacc[0] = __builtin_amdgcn_mfma_f32_16x16x32_bf16(pf[0][k2], vone, lacc[0], 0, 0, 0);
            lacc[1] = __builtin_amdgcn_mfma_f32_16x16x32_bf16(pf[1][k2], vone, lacc[1], 0, 0, 0);
        }
    }
    // epilogue
#pragma unroll
    for (int mg = 0; mg < 2; mg++) {
        float inv[4];
#pragma unroll
        for (int r = 0; r < 4; r++) inv[r] = 1.0f / lacc[mg][r];
#pragma unroll
        for (int j = 0; j < 8; j++)
#pragma unroll
            for (int r = 0; r < 4; r++) {
                const int qrow = row0 + mg * 16 + quad * 4 + r;
                attn[((size_t)(b * S_LEN) + qrow) * (NH * HD) + h * HD + j * 16 + lr] =
                    (bf16)(o[mg][j][r] * inv[r]);
            }
    }
}

extern "C" void kernel_launch(void* const* d_in, const int* in_sizes, int n_in,
                              void* d_out, int out_size, void* d_ws, size_t ws_size,
                              hipStream_t stream) {
    (void)in_sizes; (void)n_in; (void)out_size; (void)ws_size;
    const float* hs  = (const float*)d_in[0];
    const float* wq  = (const float*)d_in[1];
    const float* wk  = (const float*)d_in[2];
    const float* wv  = (const float*)d_in[3];
    const float* wo  = (const float*)d_in[4];
    const float* qnw = (const float*)d_in[5];
    const float* knw = (const float*)d_in[6];
    float* out = (float*)d_out;

    char* ws = (char*)d_ws;
    size_t off = 0;
    auto alloc = [&](size_t bytes) {
        void* p = ws + off;
        off += (bytes + 255) & ~(size_t)255;
        return p;
    };
    // NOTE: hs_bf / wqkv_bf / wo_bf must stay contiguous (cast_all writes them
    // as one flat region).
    bf16* hs_bf   = (bf16*)alloc((size_t)4096 * 2048 * 2);
    bf16* wqkv_bf = (bf16*)alloc((size_t)3072 * 2048 * 2);
    bf16* wo_bf   = (bf16*)alloc((size_t)2048 * 2048 * 2);
    bf16* qkv_bf  = (bf16*)alloc((size_t)4096 * 3072 * 2);
    bf16* q_bf    = (bf16*)alloc((size_t)B_DIM * NH * S_LEN * HD * 2);
    bf16* k_bf    = (bf16*)alloc((size_t)B_DIM * NKV * S_LEN * HD * 2);
    bf16* vt_bf   = (bf16*)alloc((size_t)B_DIM * NKV * S_LEN * HD * 2);
    bf16* at_bf   = (bf16*)alloc((size_t)4096 * 2048 * 2);

    cast_all<<<18432, 256, 0, stream>>>(hs, wq, wk, wv, wo, hs_bf);
    gemm_bt<bf16><<<dim3(32, 24), 256, 0, stream>>>(hs_bf, wqkv_bf, qkv_bf, 4096, 3072, 2048);
    rope_rms<<<4096, 256, 0, stream>>>(qkv_bf, qnw, knw, q_bf, k_bf, vt_bf);
    flash<<<dim3(512), 256, 0, stream>>>(q_bf, k_bf, vt_bf, at_bf);
    gemm_bt<float><<<dim3(32, 16), 256, 0, stream>>>(at_bf, wo_bf, out, 4096, 2048, 2048);
}